// Round 2
// baseline (360.350 us; speedup 1.0000x reference)
//
#include <hip/hip_runtime.h>
#include <hip/hip_bf16.h>

// GraphConv 2-hop: gather(ent[tail]*rel[type]) -> scatter-mean by head -> l2norm,
// twice, with fused residual outputs. CSR built on-device each call (no float atomics).
//
// ws layout (all 4-byte units):
//   row_start : int[n_ent+1]
//   cursor    : int[n_ent]        (doubles as histogram)
//   blocksum  : int[128]
//   blockoff  : int[128]
//   packed    : int[E]            (tail | type<<17; tail<2^17, type<16)
//   ent1      : float[n_ent*64]   (hop-1 normalized output, hop-2 gather source)
//   rel1      : float[n_rel*64]   (l2norm(relation_emb))

#define WAVE 64

__global__ void hist_kernel(const int* __restrict__ heads, int* __restrict__ hist, int E) {
    for (int e = blockIdx.x * blockDim.x + threadIdx.x; e < E; e += gridDim.x * blockDim.x)
        atomicAdd(&hist[heads[e]], 1);
}

// Exclusive scan within each 1024-chunk; optional per-block totals.
__global__ void scan_block(const int* __restrict__ in, int* __restrict__ out_excl,
                           int* __restrict__ blocksum, int n) {
    __shared__ int wsum[16];
    const int tid = threadIdx.x;
    const int gi = blockIdx.x * 1024 + tid;
    const int lane = tid & 63, wid = tid >> 6;
    int v = (gi < n) ? in[gi] : 0;
    int s = v;
#pragma unroll
    for (int off = 1; off < 64; off <<= 1) {
        int t = __shfl_up(s, off);
        if (lane >= off) s += t;
    }
    if (lane == 63) wsum[wid] = s;
    __syncthreads();
    if (wid == 0) {
        int ws = (lane < 16) ? wsum[lane] : 0;
#pragma unroll
        for (int off = 1; off < 16; off <<= 1) {
            int t = __shfl_up(ws, off);
            if (lane >= off) ws += t;
        }
        if (lane < 16) wsum[lane] = ws;
        if (lane == 15 && blocksum) blocksum[blockIdx.x] = ws;
    }
    __syncthreads();
    int wave_off = (wid > 0) ? wsum[wid - 1] : 0;
    if (gi < n) out_excl[gi] = s - v + wave_off;
}

__global__ void scan_fixup(int* __restrict__ row_start, int* __restrict__ cursor,
                           const int* __restrict__ blockoff, int n, int E) {
    int gi = blockIdx.x * blockDim.x + threadIdx.x;
    if (gi < n) {
        int v = row_start[gi] + blockoff[gi >> 10];
        row_start[gi] = v;
        cursor[gi] = v;
    }
    if (gi == n) row_start[n] = E;
}

__global__ void scatter_kernel(const int* __restrict__ heads, const int* __restrict__ tails,
                               const int* __restrict__ etype, int* __restrict__ cursor,
                               int* __restrict__ packed, int E) {
    for (int e = blockIdx.x * blockDim.x + threadIdx.x; e < E; e += gridDim.x * blockDim.x) {
        int h = heads[e];
        int t = tails[e];
        int ty = etype[e];
        int pos = atomicAdd(&cursor[h], 1);
        packed[pos] = t | (ty << 17);
    }
}

// One wave per entity row; lane = channel. FINAL=false: write ent1 (hop-1).
// FINAL=true: write ent_res / drug_res directly (hop-2).
// Inner gather loop 4-way unrolled with 4 independent accumulators: 4 L2-latency
// gathers in flight per wave instead of 1, fma chain broken.
template <bool FINAL>
__global__ void hop_kernel(const float* __restrict__ ent_src,   // gather source
                           const float* __restrict__ rel_src,   // 16x64 message weights
                           const int* __restrict__ row_start,
                           const int* __restrict__ packed,
                           float* __restrict__ ent_next,        // FINAL=false
                           const float* __restrict__ ent0,      // FINAL=true: entity_emb
                           const float* __restrict__ drug0,     // FINAL=true: drug_emb
                           float* __restrict__ out_ent,         // FINAL=true
                           float* __restrict__ out_drug,        // FINAL=true
                           int n_rows, int n_drugs) {
    __shared__ float rel_lds[16 * 64];
    for (int i = threadIdx.x; i < 16 * 64; i += blockDim.x) rel_lds[i] = rel_src[i];
    __syncthreads();

    const int lane = threadIdx.x & 63;
    const int wave = blockIdx.x * (blockDim.x >> 6) + (threadIdx.x >> 6);
    const int nw = gridDim.x * (blockDim.x >> 6);

    for (int r = wave; r < n_rows; r += nw) {
        const int start = row_start[r];
        const int deg = row_start[r + 1] - start;
        float acc0 = 0.f, acc1 = 0.f, acc2 = 0.f, acc3 = 0.f;
        for (int base = 0; base < deg; base += WAVE) {
            int rem = deg - base;
            if (rem > WAVE) rem = WAVE;
            int pk = 0;
            if (lane < rem) pk = packed[start + base + lane];
            int e = 0;
            for (; e + 3 < rem; e += 4) {
                int p0 = __shfl(pk, e);
                int p1 = __shfl(pk, e + 1);
                int p2 = __shfl(pk, e + 2);
                int p3 = __shfl(pk, e + 3);
                const float* s0 = ent_src + (size_t)(p0 & 131071) * 64;
                const float* s1 = ent_src + (size_t)(p1 & 131071) * 64;
                const float* s2 = ent_src + (size_t)(p2 & 131071) * 64;
                const float* s3 = ent_src + (size_t)(p3 & 131071) * 64;
                float v0 = s0[lane], v1 = s1[lane], v2 = s2[lane], v3 = s3[lane];
                acc0 = fmaf(v0, rel_lds[(p0 >> 17) * 64 + lane], acc0);
                acc1 = fmaf(v1, rel_lds[(p1 >> 17) * 64 + lane], acc1);
                acc2 = fmaf(v2, rel_lds[(p2 >> 17) * 64 + lane], acc2);
                acc3 = fmaf(v3, rel_lds[(p3 >> 17) * 64 + lane], acc3);
            }
            for (; e < rem; ++e) {
                int p = __shfl(pk, e);
                acc0 = fmaf(ent_src[(size_t)(p & 131071) * 64 + lane],
                            rel_lds[(p >> 17) * 64 + lane], acc0);
            }
        }
        float acc = (acc0 + acc1) + (acc2 + acc3);
        float denom = (float)(deg > 0 ? deg : 1);
        float a = acc / denom;
        float ss = a * a;
#pragma unroll
        for (int off = 32; off > 0; off >>= 1) ss += __shfl_xor(ss, off);
        float inv = 1.0f / fmaxf(sqrtf(ss), 1e-12f);
        float e2 = a * inv;
        if (!FINAL) {
            ent_next[r * 64 + lane] = e2;
        } else {
            float e1 = ent_src[r * 64 + lane];     // ent1 row (gather source == ent1)
            float sum12 = e1 + e2;
            out_ent[r * 64 + lane] = ent0[r * 64 + lane] + sum12;
            if (r < n_drugs)
                out_drug[r * 64 + lane] = drug0[r * 64 + lane] + sum12;
        }
    }
}

// rel1 = l2norm(rel0); rel2 = l2norm(rel1); rel_res = rel0 + rel1 + rel2.
__global__ void rel_kernel(const float* __restrict__ rel0, float* __restrict__ rel1_out,
                           float* __restrict__ out_rel, int n_rel) {
    int lane = threadIdx.x & 63;
    int wave = threadIdx.x >> 6;
    if (wave >= n_rel) return;
    float v = rel0[wave * 64 + lane];
    float ss = v * v;
#pragma unroll
    for (int off = 32; off > 0; off >>= 1) ss += __shfl_xor(ss, off);
    float r1 = v / fmaxf(sqrtf(ss), 1e-12f);
    float ss2 = r1 * r1;
#pragma unroll
    for (int off = 32; off > 0; off >>= 1) ss2 += __shfl_xor(ss2, off);
    float r2 = r1 / fmaxf(sqrtf(ss2), 1e-12f);
    rel1_out[wave * 64 + lane] = r1;
    out_rel[wave * 64 + lane] = v + r1 + r2;
}

extern "C" void kernel_launch(void* const* d_in, const int* in_sizes, int n_in,
                              void* d_out, int out_size, void* d_ws, size_t ws_size,
                              hipStream_t stream) {
    const float* drug_emb = (const float*)d_in[0];
    const float* entity_emb = (const float*)d_in[1];
    const float* relation_emb = (const float*)d_in[2];
    const int* edge_index = (const int*)d_in[3];
    const int* edge_type = (const int*)d_in[4];

    const int n_drugs = in_sizes[0] / 64;   // 2000
    const int n_ent = in_sizes[1] / 64;     // 100000
    const int n_rel = in_sizes[2] / 64;     // 16
    const int E = in_sizes[4];              // 1250000

    const int* heads = edge_index;          // edge_index[0, :]
    const int* tails = edge_index + E;      // edge_index[1, :]

    int* row_start = (int*)d_ws;                      // n_ent+1
    int* cursor = row_start + (n_ent + 1);            // n_ent
    int* blocksum = cursor + n_ent;                   // 128
    int* blockoff = blocksum + 128;                   // 128
    int* packed = blockoff + 128;                     // E
    float* ent1 = (float*)(packed + E);               // n_ent*64
    float* rel1 = ent1 + (size_t)n_ent * 64;          // n_rel*64

    float* out_ent = (float*)d_out;
    float* out_drug = out_ent + (size_t)n_ent * 64;
    float* out_rel = out_drug + (size_t)n_drugs * 64;

    const int nscan = (n_ent + 1023) / 1024;          // 98

    hipMemsetAsync(cursor, 0, (size_t)n_ent * sizeof(int), stream);
    hist_kernel<<<1024, 256, 0, stream>>>(heads, cursor, E);
    scan_block<<<nscan, 1024, 0, stream>>>(cursor, row_start, blocksum, n_ent);
    scan_block<<<1, 1024, 0, stream>>>(blocksum, blockoff, nullptr, nscan);
    scan_fixup<<<(n_ent + 256) / 256, 256, 0, stream>>>(row_start, cursor, blockoff, n_ent, E);
    scatter_kernel<<<1024, 256, 0, stream>>>(heads, tails, edge_type, cursor, packed, E);
    hop_kernel<false><<<2048, 256, 0, stream>>>(entity_emb, relation_emb, row_start, packed,
                                                ent1, nullptr, nullptr, nullptr, nullptr,
                                                n_ent, 0);
    rel_kernel<<<1, 1024, 0, stream>>>(relation_emb, rel1, out_rel, n_rel);
    hop_kernel<true><<<2048, 256, 0, stream>>>(ent1, rel1, row_start, packed,
                                               nullptr, entity_emb, drug_emb,
                                               out_ent, out_drug, n_ent, n_drugs);
}

// Round 3
// 251.181 us; speedup vs baseline: 1.4346x; 1.4346x over previous
//
#include <hip/hip_runtime.h>
#include <hip/hip_bf16.h>

// GraphConv 2-hop: gather(ent[tail]*rel[type]) -> scatter-mean by head -> l2norm,
// twice, fused residual outputs.
//
// CSR built per-call via a deterministic two-level counting sort (NO global
// atomics, NO random 4B scatters — Round-2 profile showed the atomic scatter
// cost 92us with 17x write amplification from cross-XCD false sharing):
//   A: per-chunk LDS histogram over 391 head-buckets (bucket = head>>8)
//   B: flat exclusive scan of G[(bucket,chunk)] -> disjoint contiguous ranges
//   C: place (head,payload) 8B entries into owned ranges (full-line writes)
//   D: per-bucket block: LDS degree count + scan -> row_start, then final
//      placement into a ~13KB contiguous CSR window (L2-local)
//
// ws layout (ints): packed[E] | union{staging int2[E], ent1 f32[n_ent*64]} |
//                   G[L] | Gscan[L] | blocksum[128] | blockoff[128] |
//                   row_start[n_ent+1] | rel1 f32[n_rel*64]

#define CHUNK 8192
#define ABLOCK 512
#define BSHIFT 8
#define BMASK 255

// ---- A: per-chunk bucket histogram (LDS atomics only) ----
__global__ void local_hist_kernel(const int* __restrict__ heads, int* __restrict__ G,
                                  int E, int nchunks, int nb) {
    __shared__ int hist[512];
    for (int i = threadIdx.x; i < nb; i += blockDim.x) hist[i] = 0;
    __syncthreads();
    const int blk = blockIdx.x;
    const int lo = blk * CHUNK;
    const int hi = min(lo + CHUNK, E);
    for (int i = lo + threadIdx.x; i < hi; i += blockDim.x)
        atomicAdd(&hist[heads[i] >> BSHIFT], 1);
    __syncthreads();
    for (int b = threadIdx.x; b < nb; b += blockDim.x)
        G[b * nchunks + blk] = hist[b];
}

// ---- B: exclusive scan (1024-chunk blocks + block-offset fixup) ----
__global__ void scan_block(const int* __restrict__ in, int* __restrict__ out_excl,
                           int* __restrict__ blocksum, int n) {
    __shared__ int wsum[16];
    const int tid = threadIdx.x;
    const int gi = blockIdx.x * 1024 + tid;
    const int lane = tid & 63, wid = tid >> 6;
    int v = (gi < n) ? in[gi] : 0;
    int s = v;
#pragma unroll
    for (int off = 1; off < 64; off <<= 1) {
        int t = __shfl_up(s, off);
        if (lane >= off) s += t;
    }
    if (lane == 63) wsum[wid] = s;
    __syncthreads();
    if (wid == 0) {
        int ws = (lane < 16) ? wsum[lane] : 0;
#pragma unroll
        for (int off = 1; off < 16; off <<= 1) {
            int t = __shfl_up(ws, off);
            if (lane >= off) ws += t;
        }
        if (lane < 16) wsum[lane] = ws;
        if (lane == 15 && blocksum) blocksum[blockIdx.x] = ws;
    }
    __syncthreads();
    int wave_off = (wid > 0) ? wsum[wid - 1] : 0;
    if (gi < n) out_excl[gi] = s - v + wave_off;
}

__global__ void gscan_fixup(int* __restrict__ g, const int* __restrict__ blockoff, int n) {
    int gi = blockIdx.x * blockDim.x + threadIdx.x;
    if (gi < n) g[gi] += blockoff[gi >> 10];
}

// ---- C: place edges into per-(chunk,bucket) disjoint staging ranges ----
__global__ void place_stage_kernel(const int* __restrict__ heads, const int* __restrict__ tails,
                                   const int* __restrict__ etype, const int* __restrict__ Gscan,
                                   int2* __restrict__ staging, int E, int nchunks, int nb) {
    __shared__ int cur[512];
    const int blk = blockIdx.x;
    for (int b = threadIdx.x; b < nb; b += blockDim.x)
        cur[b] = Gscan[b * nchunks + blk];
    __syncthreads();
    const int lo = blk * CHUNK;
    const int hi = min(lo + CHUNK, E);
    for (int i = lo + threadIdx.x; i < hi; i += blockDim.x) {
        int h = heads[i];
        int payload = tails[i] | (etype[i] << 17);
        int pos = atomicAdd(&cur[h >> BSHIFT], 1);
        staging[pos] = make_int2(h, payload);
    }
}

// ---- D: per-bucket degree count + scan -> row_start; final CSR placement ----
__global__ void finalize_kernel(const int2* __restrict__ staging, const int* __restrict__ Gscan,
                                int* __restrict__ packed, int* __restrict__ row_start,
                                int E, int nchunks, int nb, int n_ent) {
    __shared__ int deg[256], pos[256], cur[256];
    const int b = blockIdx.x;
    const int tid = threadIdx.x;              // 256 threads
    const int head_lo = b << BSHIFT;
    const int seg_start = Gscan[b * nchunks];
    const int seg_end = (b + 1 < nb) ? Gscan[(b + 1) * nchunks] : E;
    deg[tid] = 0;
    __syncthreads();
    for (int i = seg_start + tid; i < seg_end; i += 256) {
        int2 v = staging[i];
        atomicAdd(&deg[v.x & BMASK], 1);
    }
    __syncthreads();
    pos[tid] = deg[tid];
    __syncthreads();
    for (int off = 1; off < 256; off <<= 1) {
        int t = (tid >= off) ? pos[tid - off] : 0;
        __syncthreads();
        pos[tid] += t;
        __syncthreads();
    }
    const int excl = pos[tid] - deg[tid];
    const int h = head_lo + tid;
    if (h < n_ent) row_start[h] = seg_start + excl;
    if (b == 0 && tid == 0) row_start[n_ent] = E;
    cur[tid] = seg_start + excl;
    __syncthreads();
    for (int i = seg_start + tid; i < seg_end; i += 256) {
        int2 v = staging[i];
        int p = atomicAdd(&cur[v.x & BMASK], 1);
        packed[p] = v.y;
    }
}

// ---- hop: one wave per entity row; lane = channel; 4-way unrolled gathers ----
template <bool FINAL>
__global__ void hop_kernel(const float* __restrict__ ent_src,
                           const float* __restrict__ rel_src,
                           const int* __restrict__ row_start,
                           const int* __restrict__ packed,
                           float* __restrict__ ent_next,
                           const float* __restrict__ ent0,
                           const float* __restrict__ drug0,
                           float* __restrict__ out_ent,
                           float* __restrict__ out_drug,
                           int n_rows, int n_drugs) {
    __shared__ float rel_lds[16 * 64];
    for (int i = threadIdx.x; i < 16 * 64; i += blockDim.x) rel_lds[i] = rel_src[i];
    __syncthreads();

    const int lane = threadIdx.x & 63;
    const int wave = blockIdx.x * (blockDim.x >> 6) + (threadIdx.x >> 6);
    const int nw = gridDim.x * (blockDim.x >> 6);

    for (int r = wave; r < n_rows; r += nw) {
        const int start = row_start[r];
        const int deg = row_start[r + 1] - start;
        float acc0 = 0.f, acc1 = 0.f, acc2 = 0.f, acc3 = 0.f;
        for (int base = 0; base < deg; base += 64) {
            int rem = deg - base;
            if (rem > 64) rem = 64;
            int pk = 0;
            if (lane < rem) pk = packed[start + base + lane];
            int e = 0;
            for (; e + 3 < rem; e += 4) {
                int p0 = __shfl(pk, e);
                int p1 = __shfl(pk, e + 1);
                int p2 = __shfl(pk, e + 2);
                int p3 = __shfl(pk, e + 3);
                float v0 = ent_src[(size_t)(p0 & 131071) * 64 + lane];
                float v1 = ent_src[(size_t)(p1 & 131071) * 64 + lane];
                float v2 = ent_src[(size_t)(p2 & 131071) * 64 + lane];
                float v3 = ent_src[(size_t)(p3 & 131071) * 64 + lane];
                acc0 = fmaf(v0, rel_lds[(p0 >> 17) * 64 + lane], acc0);
                acc1 = fmaf(v1, rel_lds[(p1 >> 17) * 64 + lane], acc1);
                acc2 = fmaf(v2, rel_lds[(p2 >> 17) * 64 + lane], acc2);
                acc3 = fmaf(v3, rel_lds[(p3 >> 17) * 64 + lane], acc3);
            }
            for (; e < rem; ++e) {
                int p = __shfl(pk, e);
                acc0 = fmaf(ent_src[(size_t)(p & 131071) * 64 + lane],
                            rel_lds[(p >> 17) * 64 + lane], acc0);
            }
        }
        float acc = (acc0 + acc1) + (acc2 + acc3);
        float denom = (float)(deg > 0 ? deg : 1);
        float a = acc / denom;
        float ss = a * a;
#pragma unroll
        for (int off = 32; off > 0; off >>= 1) ss += __shfl_xor(ss, off);
        float inv = 1.0f / fmaxf(sqrtf(ss), 1e-12f);
        float e2 = a * inv;
        if (!FINAL) {
            ent_next[r * 64 + lane] = e2;
        } else {
            float e1 = ent_src[r * 64 + lane];
            float sum12 = e1 + e2;
            out_ent[r * 64 + lane] = ent0[r * 64 + lane] + sum12;
            if (r < n_drugs)
                out_drug[r * 64 + lane] = drug0[r * 64 + lane] + sum12;
        }
    }
}

// rel1 = l2norm(rel0); rel2 = l2norm(rel1) (= rel1); rel_res = rel0 + rel1 + rel2.
__global__ void rel_kernel(const float* __restrict__ rel0, float* __restrict__ rel1_out,
                           float* __restrict__ out_rel, int n_rel) {
    int lane = threadIdx.x & 63;
    int wave = threadIdx.x >> 6;
    if (wave >= n_rel) return;
    float v = rel0[wave * 64 + lane];
    float ss = v * v;
#pragma unroll
    for (int off = 32; off > 0; off >>= 1) ss += __shfl_xor(ss, off);
    float r1 = v / fmaxf(sqrtf(ss), 1e-12f);
    float ss2 = r1 * r1;
#pragma unroll
    for (int off = 32; off > 0; off >>= 1) ss2 += __shfl_xor(ss2, off);
    float r2 = r1 / fmaxf(sqrtf(ss2), 1e-12f);
    rel1_out[wave * 64 + lane] = r1;
    out_rel[wave * 64 + lane] = v + r1 + r2;
}

extern "C" void kernel_launch(void* const* d_in, const int* in_sizes, int n_in,
                              void* d_out, int out_size, void* d_ws, size_t ws_size,
                              hipStream_t stream) {
    const float* drug_emb = (const float*)d_in[0];
    const float* entity_emb = (const float*)d_in[1];
    const float* relation_emb = (const float*)d_in[2];
    const int* edge_index = (const int*)d_in[3];
    const int* edge_type = (const int*)d_in[4];

    const int n_drugs = in_sizes[0] / 64;   // 2000
    const int n_ent = in_sizes[1] / 64;     // 100000
    const int n_rel = in_sizes[2] / 64;     // 16
    const int E = in_sizes[4];              // 1250000

    const int* heads = edge_index;          // edge_index[0, :]
    const int* tails = edge_index + E;      // edge_index[1, :]

    const int nchunks = (E + CHUNK - 1) / CHUNK;          // 153
    const int nb = (n_ent + (1 << BSHIFT) - 1) >> BSHIFT; // 391
    const int L = nb * nchunks;                           // ~59,823
    const int nscanG = (L + 1023) / 1024;                 // ~59

    // ws carve-up (int units). staging (early) and ent1 (late) share memory.
    int* packed = (int*)d_ws;                             // E
    int* staging_base = packed + ((E + 1) & ~1);          // 8B-aligned
    int2* staging = (int2*)staging_base;                  // E int2 (2E ints)
    float* ent1 = (float*)staging_base;                   // n_ent*64 floats (union)
    size_t union_ints = (size_t)n_ent * 64;               // 6.4M >= 2E
    if (union_ints < (size_t)2 * E) union_ints = (size_t)2 * E;
    int* G = staging_base + union_ints;                   // L
    int* Gscan = G + L;                                   // L
    int* blocksum = Gscan + L;                            // 128
    int* blockoff = blocksum + 128;                       // 128
    int* row_start = blockoff + 128;                      // n_ent+1
    float* rel1 = (float*)(row_start + n_ent + 1);        // n_rel*64

    float* out_ent = (float*)d_out;
    float* out_drug = out_ent + (size_t)n_ent * 64;
    float* out_rel = out_drug + (size_t)n_drugs * 64;

    local_hist_kernel<<<nchunks, ABLOCK, 0, stream>>>(heads, G, E, nchunks, nb);
    scan_block<<<nscanG, 1024, 0, stream>>>(G, Gscan, blocksum, L);
    scan_block<<<1, 1024, 0, stream>>>(blocksum, blockoff, nullptr, nscanG);
    gscan_fixup<<<(L + 255) / 256, 256, 0, stream>>>(Gscan, blockoff, L);
    place_stage_kernel<<<nchunks, ABLOCK, 0, stream>>>(heads, tails, edge_type, Gscan,
                                                       staging, E, nchunks, nb);
    finalize_kernel<<<nb, 256, 0, stream>>>(staging, Gscan, packed, row_start,
                                            E, nchunks, nb, n_ent);
    hop_kernel<false><<<2048, 256, 0, stream>>>(entity_emb, relation_emb, row_start, packed,
                                                ent1, nullptr, nullptr, nullptr, nullptr,
                                                n_ent, 0);
    rel_kernel<<<1, 1024, 0, stream>>>(relation_emb, rel1, out_rel, n_rel);
    hop_kernel<true><<<2048, 256, 0, stream>>>(ent1, rel1, row_start, packed,
                                               nullptr, entity_emb, drug_emb,
                                               out_ent, out_drug, n_ent, n_drugs);
}

// Round 4
// 245.342 us; speedup vs baseline: 1.4688x; 1.0238x over previous
//
#include <hip/hip_runtime.h>
#include <hip/hip_bf16.h>

// GraphConv 2-hop: gather(ent[tail]*rel[type]) -> scatter-mean by head -> l2norm,
// twice, fused residual outputs.
//
// CSR built per-call via deterministic two-level counting sort (no global atomics).
// R2->R3: atomic scatter (92us, 17x write-amp) replaced by bucket sort: total 360->251us.
// R4: staging entry packed to ONE int (tail:17 | type:4 | head&255:8 = 29 bits),
//     gscan_fixup fused into consumers, hop gather loop unrolled 8-deep (MLP probe).
//
// ws layout (ints): packed[E] | union{staging int[E], ent1 f32[n_ent*64]} |
//                   G[L] | Gscan[L] | blocksum[128] | blockoff[128] |
//                   row_start[n_ent+1] | rel1 f32[n_rel*64]

#define CHUNK 8192
#define ABLOCK 512
#define BSHIFT 8
#define BMASK 255

// ---- A: per-chunk bucket histogram (LDS atomics only) ----
__global__ void local_hist_kernel(const int* __restrict__ heads, int* __restrict__ G,
                                  int E, int nchunks, int nb) {
    __shared__ int hist[512];
    for (int i = threadIdx.x; i < nb; i += blockDim.x) hist[i] = 0;
    __syncthreads();
    const int blk = blockIdx.x;
    const int lo = blk * CHUNK;
    const int hi = min(lo + CHUNK, E);
    for (int i = lo + threadIdx.x; i < hi; i += blockDim.x)
        atomicAdd(&hist[heads[i] >> BSHIFT], 1);
    __syncthreads();
    for (int b = threadIdx.x; b < nb; b += blockDim.x)
        G[b * nchunks + blk] = hist[b];
}

// ---- B: exclusive scan (1024-chunk blocks + block totals) ----
__global__ void scan_block(const int* __restrict__ in, int* __restrict__ out_excl,
                           int* __restrict__ blocksum, int n) {
    __shared__ int wsum[16];
    const int tid = threadIdx.x;
    const int gi = blockIdx.x * 1024 + tid;
    const int lane = tid & 63, wid = tid >> 6;
    int v = (gi < n) ? in[gi] : 0;
    int s = v;
#pragma unroll
    for (int off = 1; off < 64; off <<= 1) {
        int t = __shfl_up(s, off);
        if (lane >= off) s += t;
    }
    if (lane == 63) wsum[wid] = s;
    __syncthreads();
    if (wid == 0) {
        int ws = (lane < 16) ? wsum[lane] : 0;
#pragma unroll
        for (int off = 1; off < 16; off <<= 1) {
            int t = __shfl_up(ws, off);
            if (lane >= off) ws += t;
        }
        if (lane < 16) wsum[lane] = ws;
        if (lane == 15 && blocksum) blocksum[blockIdx.x] = ws;
    }
    __syncthreads();
    int wave_off = (wid > 0) ? wsum[wid - 1] : 0;
    if (gi < n) out_excl[gi] = s - v + wave_off;
}

// ---- C: place packed edges into per-(chunk,bucket) disjoint staging ranges ----
// blockoff fixup fused here (Gscan entries are pre-fixup partial scans).
__global__ void place_stage_kernel(const int* __restrict__ heads, const int* __restrict__ tails,
                                   const int* __restrict__ etype, const int* __restrict__ Gscan,
                                   const int* __restrict__ blockoff,
                                   int* __restrict__ staging, int E, int nchunks, int nb) {
    __shared__ int cur[512];
    const int blk = blockIdx.x;
    for (int b = threadIdx.x; b < nb; b += blockDim.x) {
        int idx = b * nchunks + blk;
        cur[b] = Gscan[idx] + blockoff[idx >> 10];
    }
    __syncthreads();
    const int lo = blk * CHUNK;
    const int hi = min(lo + CHUNK, E);
    for (int i = lo + threadIdx.x; i < hi; i += blockDim.x) {
        int h = heads[i];
        int entry = tails[i] | (etype[i] << 17) | ((h & BMASK) << 21);
        int pos = atomicAdd(&cur[h >> BSHIFT], 1);
        staging[pos] = entry;
    }
}

// ---- D: per-bucket degree count + scan -> row_start; final CSR placement ----
__global__ void finalize_kernel(const int* __restrict__ staging, const int* __restrict__ Gscan,
                                const int* __restrict__ blockoff,
                                int* __restrict__ packed, int* __restrict__ row_start,
                                int E, int nchunks, int nb, int n_ent) {
    __shared__ int deg[256], pos[256], cur[256];
    const int b = blockIdx.x;
    const int tid = threadIdx.x;              // 256 threads
    const int head_lo = b << BSHIFT;
    const int i0 = b * nchunks;
    const int seg_start = Gscan[i0] + blockoff[i0 >> 10];
    int seg_end = E;
    if (b + 1 < nb) {
        const int i1 = (b + 1) * nchunks;
        seg_end = Gscan[i1] + blockoff[i1 >> 10];
    }
    deg[tid] = 0;
    __syncthreads();
    for (int i = seg_start + tid; i < seg_end; i += 256)
        atomicAdd(&deg[(staging[i] >> 21) & BMASK], 1);
    __syncthreads();
    pos[tid] = deg[tid];
    __syncthreads();
    for (int off = 1; off < 256; off <<= 1) {
        int t = (tid >= off) ? pos[tid - off] : 0;
        __syncthreads();
        pos[tid] += t;
        __syncthreads();
    }
    const int excl = pos[tid] - deg[tid];
    const int h = head_lo + tid;
    if (h < n_ent) row_start[h] = seg_start + excl;
    if (b == 0 && tid == 0) row_start[n_ent] = E;
    cur[tid] = seg_start + excl;
    __syncthreads();
    for (int i = seg_start + tid; i < seg_end; i += 256) {
        int v = staging[i];
        int p = atomicAdd(&cur[(v >> 21) & BMASK], 1);
        packed[p] = v;
    }
}

// ---- hop: one wave per entity row; lane = channel; 8-deep gather pipeline ----
template <bool FINAL>
__global__ void hop_kernel(const float* __restrict__ ent_src,
                           const float* __restrict__ rel_src,
                           const int* __restrict__ row_start,
                           const int* __restrict__ packed,
                           float* __restrict__ ent_next,
                           const float* __restrict__ ent0,
                           const float* __restrict__ drug0,
                           float* __restrict__ out_ent,
                           float* __restrict__ out_drug,
                           int n_rows, int n_drugs) {
    __shared__ float rel_lds[16 * 64];
    for (int i = threadIdx.x; i < 16 * 64; i += blockDim.x) rel_lds[i] = rel_src[i];
    __syncthreads();

    const int lane = threadIdx.x & 63;
    const int wave = blockIdx.x * (blockDim.x >> 6) + (threadIdx.x >> 6);
    const int nw = gridDim.x * (blockDim.x >> 6);

    for (int r = wave; r < n_rows; r += nw) {
        const int start = row_start[r];
        const int deg = row_start[r + 1] - start;
        float acc0 = 0.f, acc1 = 0.f, acc2 = 0.f, acc3 = 0.f;
        float acc4 = 0.f, acc5 = 0.f, acc6 = 0.f, acc7 = 0.f;
        for (int base = 0; base < deg; base += 64) {
            int rem = deg - base;
            if (rem > 64) rem = 64;
            int pk = 0;
            if (lane < rem) pk = packed[start + base + lane];
            int e = 0;
            for (; e + 7 < rem; e += 8) {
                int p0 = __shfl(pk, e), p1 = __shfl(pk, e + 1);
                int p2 = __shfl(pk, e + 2), p3 = __shfl(pk, e + 3);
                int p4 = __shfl(pk, e + 4), p5 = __shfl(pk, e + 5);
                int p6 = __shfl(pk, e + 6), p7 = __shfl(pk, e + 7);
                float v0 = ent_src[(size_t)(p0 & 131071) * 64 + lane];
                float v1 = ent_src[(size_t)(p1 & 131071) * 64 + lane];
                float v2 = ent_src[(size_t)(p2 & 131071) * 64 + lane];
                float v3 = ent_src[(size_t)(p3 & 131071) * 64 + lane];
                float v4 = ent_src[(size_t)(p4 & 131071) * 64 + lane];
                float v5 = ent_src[(size_t)(p5 & 131071) * 64 + lane];
                float v6 = ent_src[(size_t)(p6 & 131071) * 64 + lane];
                float v7 = ent_src[(size_t)(p7 & 131071) * 64 + lane];
                acc0 = fmaf(v0, rel_lds[((p0 >> 17) & 15) * 64 + lane], acc0);
                acc1 = fmaf(v1, rel_lds[((p1 >> 17) & 15) * 64 + lane], acc1);
                acc2 = fmaf(v2, rel_lds[((p2 >> 17) & 15) * 64 + lane], acc2);
                acc3 = fmaf(v3, rel_lds[((p3 >> 17) & 15) * 64 + lane], acc3);
                acc4 = fmaf(v4, rel_lds[((p4 >> 17) & 15) * 64 + lane], acc4);
                acc5 = fmaf(v5, rel_lds[((p5 >> 17) & 15) * 64 + lane], acc5);
                acc6 = fmaf(v6, rel_lds[((p6 >> 17) & 15) * 64 + lane], acc6);
                acc7 = fmaf(v7, rel_lds[((p7 >> 17) & 15) * 64 + lane], acc7);
            }
            for (; e + 3 < rem; e += 4) {
                int p0 = __shfl(pk, e), p1 = __shfl(pk, e + 1);
                int p2 = __shfl(pk, e + 2), p3 = __shfl(pk, e + 3);
                float v0 = ent_src[(size_t)(p0 & 131071) * 64 + lane];
                float v1 = ent_src[(size_t)(p1 & 131071) * 64 + lane];
                float v2 = ent_src[(size_t)(p2 & 131071) * 64 + lane];
                float v3 = ent_src[(size_t)(p3 & 131071) * 64 + lane];
                acc0 = fmaf(v0, rel_lds[((p0 >> 17) & 15) * 64 + lane], acc0);
                acc1 = fmaf(v1, rel_lds[((p1 >> 17) & 15) * 64 + lane], acc1);
                acc2 = fmaf(v2, rel_lds[((p2 >> 17) & 15) * 64 + lane], acc2);
                acc3 = fmaf(v3, rel_lds[((p3 >> 17) & 15) * 64 + lane], acc3);
            }
            for (; e < rem; ++e) {
                int p = __shfl(pk, e);
                acc0 = fmaf(ent_src[(size_t)(p & 131071) * 64 + lane],
                            rel_lds[((p >> 17) & 15) * 64 + lane], acc0);
            }
        }
        float acc = ((acc0 + acc1) + (acc2 + acc3)) + ((acc4 + acc5) + (acc6 + acc7));
        float denom = (float)(deg > 0 ? deg : 1);
        float a = acc / denom;
        float ss = a * a;
#pragma unroll
        for (int off = 32; off > 0; off >>= 1) ss += __shfl_xor(ss, off);
        float inv = 1.0f / fmaxf(sqrtf(ss), 1e-12f);
        float e2 = a * inv;
        if (!FINAL) {
            ent_next[r * 64 + lane] = e2;
        } else {
            float e1 = ent_src[r * 64 + lane];
            float sum12 = e1 + e2;
            out_ent[r * 64 + lane] = ent0[r * 64 + lane] + sum12;
            if (r < n_drugs)
                out_drug[r * 64 + lane] = drug0[r * 64 + lane] + sum12;
        }
    }
}

// rel1 = l2norm(rel0); rel2 = l2norm(rel1) (= rel1); rel_res = rel0 + rel1 + rel2.
__global__ void rel_kernel(const float* __restrict__ rel0, float* __restrict__ rel1_out,
                           float* __restrict__ out_rel, int n_rel) {
    int lane = threadIdx.x & 63;
    int wave = threadIdx.x >> 6;
    if (wave >= n_rel) return;
    float v = rel0[wave * 64 + lane];
    float ss = v * v;
#pragma unroll
    for (int off = 32; off > 0; off >>= 1) ss += __shfl_xor(ss, off);
    float r1 = v / fmaxf(sqrtf(ss), 1e-12f);
    float ss2 = r1 * r1;
#pragma unroll
    for (int off = 32; off > 0; off >>= 1) ss2 += __shfl_xor(ss2, off);
    float r2 = r1 / fmaxf(sqrtf(ss2), 1e-12f);
    rel1_out[wave * 64 + lane] = r1;
    out_rel[wave * 64 + lane] = v + r1 + r2;
}

extern "C" void kernel_launch(void* const* d_in, const int* in_sizes, int n_in,
                              void* d_out, int out_size, void* d_ws, size_t ws_size,
                              hipStream_t stream) {
    const float* drug_emb = (const float*)d_in[0];
    const float* entity_emb = (const float*)d_in[1];
    const float* relation_emb = (const float*)d_in[2];
    const int* edge_index = (const int*)d_in[3];
    const int* edge_type = (const int*)d_in[4];

    const int n_drugs = in_sizes[0] / 64;   // 2000
    const int n_ent = in_sizes[1] / 64;     // 100000
    const int n_rel = in_sizes[2] / 64;     // 16
    const int E = in_sizes[4];              // 1250000

    const int* heads = edge_index;          // edge_index[0, :]
    const int* tails = edge_index + E;      // edge_index[1, :]

    const int nchunks = (E + CHUNK - 1) / CHUNK;          // 153
    const int nb = (n_ent + (1 << BSHIFT) - 1) >> BSHIFT; // 391
    const int L = nb * nchunks;                           // ~59,823
    const int nscanG = (L + 1023) / 1024;                 // ~59

    // ws carve-up (int units). staging (early) and ent1 (late) share memory.
    int* packed = (int*)d_ws;                             // E
    int* staging = packed + ((E + 1) & ~1);               // E ints (8B-aligned)
    float* ent1 = (float*)staging;                        // n_ent*64 floats (union)
    size_t union_ints = (size_t)n_ent * 64;               // 6.4M >= E
    if (union_ints < (size_t)E) union_ints = (size_t)E;
    int* G = staging + union_ints;                        // L
    int* Gscan = G + L;                                   // L
    int* blocksum = Gscan + L;                            // 128
    int* blockoff = blocksum + 128;                       // 128
    int* row_start = blockoff + 128;                      // n_ent+1
    float* rel1 = (float*)(row_start + n_ent + 1);        // n_rel*64

    float* out_ent = (float*)d_out;
    float* out_drug = out_ent + (size_t)n_ent * 64;
    float* out_rel = out_drug + (size_t)n_drugs * 64;

    local_hist_kernel<<<nchunks, ABLOCK, 0, stream>>>(heads, G, E, nchunks, nb);
    scan_block<<<nscanG, 1024, 0, stream>>>(G, Gscan, blocksum, L);
    scan_block<<<1, 1024, 0, stream>>>(blocksum, blockoff, nullptr, nscanG);
    place_stage_kernel<<<nchunks, ABLOCK, 0, stream>>>(heads, tails, edge_type, Gscan,
                                                       blockoff, staging, E, nchunks, nb);
    finalize_kernel<<<nb, 256, 0, stream>>>(staging, Gscan, blockoff, packed, row_start,
                                            E, nchunks, nb, n_ent);
    hop_kernel<false><<<2048, 256, 0, stream>>>(entity_emb, relation_emb, row_start, packed,
                                                ent1, nullptr, nullptr, nullptr, nullptr,
                                                n_ent, 0);
    rel_kernel<<<1, 1024, 0, stream>>>(relation_emb, rel1, out_rel, n_rel);
    hop_kernel<true><<<2048, 256, 0, stream>>>(ent1, rel1, row_start, packed,
                                               nullptr, entity_emb, drug_emb,
                                               out_ent, out_drug, n_ent, n_drugs);
}

// Round 6
// 238.232 us; speedup vs baseline: 1.5126x; 1.0298x over previous
//
#include <hip/hip_runtime.h>
#include <hip/hip_bf16.h>

// GraphConv 2-hop: gather(ent[tail]*rel[type]) -> scatter-mean by head -> l2norm,
// twice, fused residual outputs.
//
// R2->R3: atomic scatter (92us, 17x write-amp) -> bucket counting sort: 360->251us.
// R3->R4: 8-deep unroll: NO change (74us hops, FETCH 230MB) => hops are L2-miss-BYTE
//         bound (~3.1 TB/s fill), not latency-bound.
// R5: bf16 gather table (halves miss bytes) -> run ABORTED (core dump, no absmax).
// R6: same design, ushort4 vector stores removed from cvt (only novel construct in
//     R5); uint4 loads + manual uint2 packing. Discriminates infra-flake vs code.
//
// ws layout (ints): packed[E] | unionA{staging int[E], ent_bf16 u16[n_ent*64]} |
//                   ent1_bf16 u16[n_ent*64] | G[L] | Gscan[L] | blocksum[128] |
//                   blockoff[128] | row_start[n_ent+1] | rel1 f32[n_rel*64]
// unionA safe: staging dies at finalize_kernel; cvt writes ent_bf16 after (same stream).

#define CHUNK 8192
#define ABLOCK 512
#define BSHIFT 8
#define BMASK 255

__device__ __forceinline__ float b2f(unsigned short u) {
    return __uint_as_float(((unsigned int)u) << 16);
}
__device__ __forceinline__ unsigned int f2b_u32(float f) {  // bf16 bits in low 16, RNE
    unsigned int u = __float_as_uint(f);
    return (u + 0x7FFFu + ((u >> 16) & 1u)) >> 16;
}
__device__ __forceinline__ unsigned short f2b(float f) {
    return (unsigned short)f2b_u32(f);
}

// ---- A: per-chunk bucket histogram (LDS atomics only) ----
__global__ void local_hist_kernel(const int* __restrict__ heads, int* __restrict__ G,
                                  int E, int nchunks, int nb) {
    __shared__ int hist[512];
    for (int i = threadIdx.x; i < nb; i += blockDim.x) hist[i] = 0;
    __syncthreads();
    const int blk = blockIdx.x;
    const int lo = blk * CHUNK;
    const int hi = min(lo + CHUNK, E);
    for (int i = lo + threadIdx.x; i < hi; i += blockDim.x)
        atomicAdd(&hist[heads[i] >> BSHIFT], 1);
    __syncthreads();
    for (int b = threadIdx.x; b < nb; b += blockDim.x)
        G[b * nchunks + blk] = hist[b];
}

// ---- B: exclusive scan (1024-chunk blocks + block totals) ----
__global__ void scan_block(const int* __restrict__ in, int* __restrict__ out_excl,
                           int* __restrict__ blocksum, int n) {
    __shared__ int wsum[16];
    const int tid = threadIdx.x;
    const int gi = blockIdx.x * 1024 + tid;
    const int lane = tid & 63, wid = tid >> 6;
    int v = (gi < n) ? in[gi] : 0;
    int s = v;
#pragma unroll
    for (int off = 1; off < 64; off <<= 1) {
        int t = __shfl_up(s, off);
        if (lane >= off) s += t;
    }
    if (lane == 63) wsum[wid] = s;
    __syncthreads();
    if (wid == 0) {
        int ws = (lane < 16) ? wsum[lane] : 0;
#pragma unroll
        for (int off = 1; off < 16; off <<= 1) {
            int t = __shfl_up(ws, off);
            if (lane >= off) ws += t;
        }
        if (lane < 16) wsum[lane] = ws;
        if (lane == 15 && blocksum) blocksum[blockIdx.x] = ws;
    }
    __syncthreads();
    int wave_off = (wid > 0) ? wsum[wid - 1] : 0;
    if (gi < n) out_excl[gi] = s - v + wave_off;
}

// ---- C: place packed edges into per-(chunk,bucket) disjoint staging ranges ----
__global__ void place_stage_kernel(const int* __restrict__ heads, const int* __restrict__ tails,
                                   const int* __restrict__ etype, const int* __restrict__ Gscan,
                                   const int* __restrict__ blockoff,
                                   int* __restrict__ staging, int E, int nchunks, int nb) {
    __shared__ int cur[512];
    const int blk = blockIdx.x;
    for (int b = threadIdx.x; b < nb; b += blockDim.x) {
        int idx = b * nchunks + blk;
        cur[b] = Gscan[idx] + blockoff[idx >> 10];
    }
    __syncthreads();
    const int lo = blk * CHUNK;
    const int hi = min(lo + CHUNK, E);
    for (int i = lo + threadIdx.x; i < hi; i += blockDim.x) {
        int h = heads[i];
        int entry = tails[i] | (etype[i] << 17) | ((h & BMASK) << 21);
        int pos = atomicAdd(&cur[h >> BSHIFT], 1);
        staging[pos] = entry;
    }
}

// ---- D: per-bucket degree count + scan -> row_start; final CSR placement ----
__global__ void finalize_kernel(const int* __restrict__ staging, const int* __restrict__ Gscan,
                                const int* __restrict__ blockoff,
                                int* __restrict__ packed, int* __restrict__ row_start,
                                int E, int nchunks, int nb, int n_ent) {
    __shared__ int deg[256], pos[256], cur[256];
    const int b = blockIdx.x;
    const int tid = threadIdx.x;
    const int head_lo = b << BSHIFT;
    const int i0 = b * nchunks;
    const int seg_start = Gscan[i0] + blockoff[i0 >> 10];
    int seg_end = E;
    if (b + 1 < nb) {
        const int i1 = (b + 1) * nchunks;
        seg_end = Gscan[i1] + blockoff[i1 >> 10];
    }
    deg[tid] = 0;
    __syncthreads();
    for (int i = seg_start + tid; i < seg_end; i += 256)
        atomicAdd(&deg[(staging[i] >> 21) & BMASK], 1);
    __syncthreads();
    pos[tid] = deg[tid];
    __syncthreads();
    for (int off = 1; off < 256; off <<= 1) {
        int t = (tid >= off) ? pos[tid - off] : 0;
        __syncthreads();
        pos[tid] += t;
        __syncthreads();
    }
    const int excl = pos[tid] - deg[tid];
    const int h = head_lo + tid;
    if (h < n_ent) row_start[h] = seg_start + excl;
    if (b == 0 && tid == 0) row_start[n_ent] = E;
    cur[tid] = seg_start + excl;
    __syncthreads();
    for (int i = seg_start + tid; i < seg_end; i += 256) {
        int v = staging[i];
        int p = atomicAdd(&cur[(v >> 21) & BMASK], 1);
        packed[p] = v;
    }
}

// ---- f32 -> bf16 table conversion: uint4 in, uint2 out (no short-vector types) ----
__global__ void cvt_bf16_kernel(const uint4* __restrict__ in, uint2* __restrict__ out, int n4) {
    for (int i = blockIdx.x * blockDim.x + threadIdx.x; i < n4; i += gridDim.x * blockDim.x) {
        uint4 v = in[i];
        uint2 o;
        o.x = f2b_u32(__uint_as_float(v.x)) | (f2b_u32(__uint_as_float(v.y)) << 16);
        o.y = f2b_u32(__uint_as_float(v.z)) | (f2b_u32(__uint_as_float(v.w)) << 16);
        out[i] = o;
    }
}

// ---- hop: one wave per entity row; lane = channel; bf16 gathers, f32 accum ----
template <bool FINAL>
__global__ void hop_kernel(const unsigned short* __restrict__ ent_src,  // bf16 table
                           const float* __restrict__ rel_src,
                           const int* __restrict__ row_start,
                           const int* __restrict__ packed,
                           unsigned short* __restrict__ ent_next,       // FINAL=false (bf16)
                           const float* __restrict__ ent0,
                           const float* __restrict__ drug0,
                           float* __restrict__ out_ent,
                           float* __restrict__ out_drug,
                           int n_rows, int n_drugs) {
    __shared__ float rel_lds[16 * 64];
    for (int i = threadIdx.x; i < 16 * 64; i += blockDim.x) rel_lds[i] = rel_src[i];
    __syncthreads();

    const int lane = threadIdx.x & 63;
    const int wave = blockIdx.x * (blockDim.x >> 6) + (threadIdx.x >> 6);
    const int nw = gridDim.x * (blockDim.x >> 6);

    for (int r = wave; r < n_rows; r += nw) {
        const int start = row_start[r];
        const int deg = row_start[r + 1] - start;
        float acc0 = 0.f, acc1 = 0.f, acc2 = 0.f, acc3 = 0.f;
        float acc4 = 0.f, acc5 = 0.f, acc6 = 0.f, acc7 = 0.f;
        for (int base = 0; base < deg; base += 64) {
            int rem = deg - base;
            if (rem > 64) rem = 64;
            int pk = 0;
            if (lane < rem) pk = packed[start + base + lane];
            int e = 0;
            for (; e + 7 < rem; e += 8) {
                int p0 = __shfl(pk, e), p1 = __shfl(pk, e + 1);
                int p2 = __shfl(pk, e + 2), p3 = __shfl(pk, e + 3);
                int p4 = __shfl(pk, e + 4), p5 = __shfl(pk, e + 5);
                int p6 = __shfl(pk, e + 6), p7 = __shfl(pk, e + 7);
                float v0 = b2f(ent_src[(size_t)(p0 & 131071) * 64 + lane]);
                float v1 = b2f(ent_src[(size_t)(p1 & 131071) * 64 + lane]);
                float v2 = b2f(ent_src[(size_t)(p2 & 131071) * 64 + lane]);
                float v3 = b2f(ent_src[(size_t)(p3 & 131071) * 64 + lane]);
                float v4 = b2f(ent_src[(size_t)(p4 & 131071) * 64 + lane]);
                float v5 = b2f(ent_src[(size_t)(p5 & 131071) * 64 + lane]);
                float v6 = b2f(ent_src[(size_t)(p6 & 131071) * 64 + lane]);
                float v7 = b2f(ent_src[(size_t)(p7 & 131071) * 64 + lane]);
                acc0 = fmaf(v0, rel_lds[((p0 >> 17) & 15) * 64 + lane], acc0);
                acc1 = fmaf(v1, rel_lds[((p1 >> 17) & 15) * 64 + lane], acc1);
                acc2 = fmaf(v2, rel_lds[((p2 >> 17) & 15) * 64 + lane], acc2);
                acc3 = fmaf(v3, rel_lds[((p3 >> 17) & 15) * 64 + lane], acc3);
                acc4 = fmaf(v4, rel_lds[((p4 >> 17) & 15) * 64 + lane], acc4);
                acc5 = fmaf(v5, rel_lds[((p5 >> 17) & 15) * 64 + lane], acc5);
                acc6 = fmaf(v6, rel_lds[((p6 >> 17) & 15) * 64 + lane], acc6);
                acc7 = fmaf(v7, rel_lds[((p7 >> 17) & 15) * 64 + lane], acc7);
            }
            for (; e < rem; ++e) {
                int p = __shfl(pk, e);
                acc0 = fmaf(b2f(ent_src[(size_t)(p & 131071) * 64 + lane]),
                            rel_lds[((p >> 17) & 15) * 64 + lane], acc0);
            }
        }
        float acc = ((acc0 + acc1) + (acc2 + acc3)) + ((acc4 + acc5) + (acc6 + acc7));
        float denom = (float)(deg > 0 ? deg : 1);
        float a = acc / denom;
        float ss = a * a;
#pragma unroll
        for (int off = 32; off > 0; off >>= 1) ss += __shfl_xor(ss, off);
        float inv = 1.0f / fmaxf(sqrtf(ss), 1e-12f);
        float e2 = a * inv;
        if (!FINAL) {
            ent_next[r * 64 + lane] = f2b(e2);
        } else {
            float e1 = b2f(ent_src[r * 64 + lane]);   // ent1 row (bf16)
            float sum12 = e1 + e2;
            out_ent[r * 64 + lane] = ent0[r * 64 + lane] + sum12;
            if (r < n_drugs)
                out_drug[r * 64 + lane] = drug0[r * 64 + lane] + sum12;
        }
    }
}

// rel1 = l2norm(rel0); rel2 = l2norm(rel1) (= rel1); rel_res = rel0 + rel1 + rel2.
__global__ void rel_kernel(const float* __restrict__ rel0, float* __restrict__ rel1_out,
                           float* __restrict__ out_rel, int n_rel) {
    int lane = threadIdx.x & 63;
    int wave = threadIdx.x >> 6;
    if (wave >= n_rel) return;
    float v = rel0[wave * 64 + lane];
    float ss = v * v;
#pragma unroll
    for (int off = 32; off > 0; off >>= 1) ss += __shfl_xor(ss, off);
    float r1 = v / fmaxf(sqrtf(ss), 1e-12f);
    float ss2 = r1 * r1;
#pragma unroll
    for (int off = 32; off > 0; off >>= 1) ss2 += __shfl_xor(ss2, off);
    float r2 = r1 / fmaxf(sqrtf(ss2), 1e-12f);
    rel1_out[wave * 64 + lane] = r1;
    out_rel[wave * 64 + lane] = v + r1 + r2;
}

extern "C" void kernel_launch(void* const* d_in, const int* in_sizes, int n_in,
                              void* d_out, int out_size, void* d_ws, size_t ws_size,
                              hipStream_t stream) {
    const float* drug_emb = (const float*)d_in[0];
    const float* entity_emb = (const float*)d_in[1];
    const float* relation_emb = (const float*)d_in[2];
    const int* edge_index = (const int*)d_in[3];
    const int* edge_type = (const int*)d_in[4];

    const int n_drugs = in_sizes[0] / 64;   // 2000
    const int n_ent = in_sizes[1] / 64;     // 100000
    const int n_rel = in_sizes[2] / 64;     // 16
    const int E = in_sizes[4];              // 1250000

    const int* heads = edge_index;
    const int* tails = edge_index + E;

    const int nchunks = (E + CHUNK - 1) / CHUNK;          // 153
    const int nb = (n_ent + (1 << BSHIFT) - 1) >> BSHIFT; // 391
    const int L = nb * nchunks;                           // ~59,823
    const int nscanG = (L + 1023) / 1024;                 // ~59

    // ws carve-up (int units).
    int* packed = (int*)d_ws;                             // E
    int* unionA = packed + ((E + 1) & ~1);                // max(E, n_ent*32) ints
    int* staging = unionA;                                // E ints (dies at finalize)
    unsigned short* ent_bf16 = (unsigned short*)unionA;   // n_ent*64 u16 (born after)
    size_t unionA_ints = (size_t)n_ent * 32;              // 3.2M >= E
    if (unionA_ints < (size_t)E) unionA_ints = (size_t)E;
    unsigned short* ent1 = (unsigned short*)(unionA + unionA_ints);  // n_ent*64 u16
    int* G = unionA + unionA_ints + (size_t)n_ent * 32;   // L
    int* Gscan = G + L;                                   // L
    int* blocksum = Gscan + L;                            // 128
    int* blockoff = blocksum + 128;                       // 128
    int* row_start = blockoff + 128;                      // n_ent+1
    float* rel1 = (float*)(row_start + n_ent + 1);        // n_rel*64

    float* out_ent = (float*)d_out;
    float* out_drug = out_ent + (size_t)n_ent * 64;
    float* out_rel = out_drug + (size_t)n_drugs * 64;

    local_hist_kernel<<<nchunks, ABLOCK, 0, stream>>>(heads, G, E, nchunks, nb);
    scan_block<<<nscanG, 1024, 0, stream>>>(G, Gscan, blocksum, L);
    scan_block<<<1, 1024, 0, stream>>>(blocksum, blockoff, nullptr, nscanG);
    place_stage_kernel<<<nchunks, ABLOCK, 0, stream>>>(heads, tails, edge_type, Gscan,
                                                       blockoff, staging, E, nchunks, nb);
    finalize_kernel<<<nb, 256, 0, stream>>>(staging, Gscan, blockoff, packed, row_start,
                                            E, nchunks, nb, n_ent);
    // staging is dead now; convert entity table into its space (stream-ordered).
    cvt_bf16_kernel<<<2048, 256, 0, stream>>>((const uint4*)entity_emb,
                                              (uint2*)ent_bf16, n_ent * 16);
    hop_kernel<false><<<2048, 256, 0, stream>>>(ent_bf16, relation_emb, row_start, packed,
                                                ent1, nullptr, nullptr, nullptr, nullptr,
                                                n_ent, 0);
    rel_kernel<<<1, 1024, 0, stream>>>(relation_emb, rel1, out_rel, n_rel);
    hop_kernel<true><<<2048, 256, 0, stream>>>(ent1, rel1, row_start, packed,
                                               nullptr, entity_emb, drug_emb,
                                               out_ent, out_drug, n_ent, n_drugs);
}

// Round 8
// 223.528 us; speedup vs baseline: 1.6121x; 1.0658x over previous
//
#include <hip/hip_runtime.h>
#include <hip/hip_bf16.h>

// GraphConv 2-hop: gather(ent[tail]*rel[type]) -> scatter-mean by head -> l2norm,
// twice, fused residual outputs.
//
// R2->R3: atomic scatter (92us, 17x write-amp) -> bucket counting sort: 360->251us.
// R3->R4: 8-deep unroll: NO change => hops not latency-bound at depth 4.
// R4->R6: bf16 gather table: hops 74->57us, FETCH 230->142MB, absmax 0.03125 (pass).
//         BW dropped 3.1->2.5 TB/s => mixed regime: part per-edge-instruction-bound.
// R7/R8: pair-edge hop — bf16 row=128B=32 lanes x uint, so wave handles 2 edges per
//     instruction (lanes 0-31 edge A, 32-63 edge B): VMEM/shfl/LDS ops halved,
//     same bytes. finalize_kernel widened to 512 threads. (R7 never ran: infra.)
//
// ws layout (ints): packed[E] | unionA{staging int[E], ent_bf16 u16[n_ent*64]} |
//                   ent1_bf16 u16[n_ent*64] | G[L] | Gscan[L] | blocksum[128] |
//                   blockoff[128] | row_start[n_ent+1] | rel1 f32[n_rel*64]
// unionA safe: staging dies at finalize_kernel; cvt writes ent_bf16 after (same stream).

#define CHUNK 8192
#define ABLOCK 512
#define BSHIFT 8
#define BMASK 255

__device__ __forceinline__ float b2f(unsigned int u16bits) {
    return __uint_as_float(u16bits << 16);
}
__device__ __forceinline__ unsigned int f2b_u32(float f) {  // bf16 bits in low 16, RNE
    unsigned int u = __float_as_uint(f);
    return (u + 0x7FFFu + ((u >> 16) & 1u)) >> 16;
}

// ---- A: per-chunk bucket histogram (LDS atomics only) ----
__global__ void local_hist_kernel(const int* __restrict__ heads, int* __restrict__ G,
                                  int E, int nchunks, int nb) {
    __shared__ int hist[512];
    for (int i = threadIdx.x; i < nb; i += blockDim.x) hist[i] = 0;
    __syncthreads();
    const int blk = blockIdx.x;
    const int lo = blk * CHUNK;
    const int hi = min(lo + CHUNK, E);
    for (int i = lo + threadIdx.x; i < hi; i += blockDim.x)
        atomicAdd(&hist[heads[i] >> BSHIFT], 1);
    __syncthreads();
    for (int b = threadIdx.x; b < nb; b += blockDim.x)
        G[b * nchunks + blk] = hist[b];
}

// ---- B: exclusive scan (1024-chunk blocks + block totals) ----
__global__ void scan_block(const int* __restrict__ in, int* __restrict__ out_excl,
                           int* __restrict__ blocksum, int n) {
    __shared__ int wsum[16];
    const int tid = threadIdx.x;
    const int gi = blockIdx.x * 1024 + tid;
    const int lane = tid & 63, wid = tid >> 6;
    int v = (gi < n) ? in[gi] : 0;
    int s = v;
#pragma unroll
    for (int off = 1; off < 64; off <<= 1) {
        int t = __shfl_up(s, off);
        if (lane >= off) s += t;
    }
    if (lane == 63) wsum[wid] = s;
    __syncthreads();
    if (wid == 0) {
        int ws = (lane < 16) ? wsum[lane] : 0;
#pragma unroll
        for (int off = 1; off < 16; off <<= 1) {
            int t = __shfl_up(ws, off);
            if (lane >= off) ws += t;
        }
        if (lane < 16) wsum[lane] = ws;
        if (lane == 15 && blocksum) blocksum[blockIdx.x] = ws;
    }
    __syncthreads();
    int wave_off = (wid > 0) ? wsum[wid - 1] : 0;
    if (gi < n) out_excl[gi] = s - v + wave_off;
}

// ---- C: place packed edges into per-(chunk,bucket) disjoint staging ranges ----
__global__ void place_stage_kernel(const int* __restrict__ heads, const int* __restrict__ tails,
                                   const int* __restrict__ etype, const int* __restrict__ Gscan,
                                   const int* __restrict__ blockoff,
                                   int* __restrict__ staging, int E, int nchunks, int nb) {
    __shared__ int cur[512];
    const int blk = blockIdx.x;
    for (int b = threadIdx.x; b < nb; b += blockDim.x) {
        int idx = b * nchunks + blk;
        cur[b] = Gscan[idx] + blockoff[idx >> 10];
    }
    __syncthreads();
    const int lo = blk * CHUNK;
    const int hi = min(lo + CHUNK, E);
    for (int i = lo + threadIdx.x; i < hi; i += blockDim.x) {
        int h = heads[i];
        int entry = tails[i] | (etype[i] << 17) | ((h & BMASK) << 21);
        int pos = atomicAdd(&cur[h >> BSHIFT], 1);
        staging[pos] = entry;
    }
}

// ---- D: per-bucket degree count + scan -> row_start; final CSR placement ----
// 512 threads: memory passes stride 512; the 256-entry scan uses tid<256 only.
__global__ void finalize_kernel(const int* __restrict__ staging, const int* __restrict__ Gscan,
                                const int* __restrict__ blockoff,
                                int* __restrict__ packed, int* __restrict__ row_start,
                                int E, int nchunks, int nb, int n_ent) {
    __shared__ int deg[256], pos[256], cur[256];
    const int b = blockIdx.x;
    const int tid = threadIdx.x;              // 512 threads
    const int head_lo = b << BSHIFT;
    const int i0 = b * nchunks;
    const int seg_start = Gscan[i0] + blockoff[i0 >> 10];
    int seg_end = E;
    if (b + 1 < nb) {
        const int i1 = (b + 1) * nchunks;
        seg_end = Gscan[i1] + blockoff[i1 >> 10];
    }
    if (tid < 256) deg[tid] = 0;
    __syncthreads();
    for (int i = seg_start + tid; i < seg_end; i += 512)
        atomicAdd(&deg[(staging[i] >> 21) & BMASK], 1);
    __syncthreads();
    if (tid < 256) pos[tid] = deg[tid];
    __syncthreads();
    for (int off = 1; off < 256; off <<= 1) {
        int t = (tid >= off && tid < 256) ? pos[tid - off] : 0;
        __syncthreads();
        if (tid < 256) pos[tid] += t;
        __syncthreads();
    }
    if (tid < 256) {
        const int excl = pos[tid] - deg[tid];
        const int h = head_lo + tid;
        if (h < n_ent) row_start[h] = seg_start + excl;
        cur[tid] = seg_start + excl;
    }
    if (b == 0 && tid == 0) row_start[n_ent] = E;
    __syncthreads();
    for (int i = seg_start + tid; i < seg_end; i += 512) {
        int v = staging[i];
        int p = atomicAdd(&cur[(v >> 21) & BMASK], 1);
        packed[p] = v;
    }
}

// ---- f32 -> bf16 table conversion: uint4 in, uint2 out ----
__global__ void cvt_bf16_kernel(const uint4* __restrict__ in, uint2* __restrict__ out, int n4) {
    for (int i = blockIdx.x * blockDim.x + threadIdx.x; i < n4; i += gridDim.x * blockDim.x) {
        uint4 v = in[i];
        uint2 o;
        o.x = f2b_u32(__uint_as_float(v.x)) | (f2b_u32(__uint_as_float(v.y)) << 16);
        o.y = f2b_u32(__uint_as_float(v.z)) | (f2b_u32(__uint_as_float(v.w)) << 16);
        out[i] = o;
    }
}

// ---- hop: one wave per row; lanes 0-31 = edge A, 32-63 = edge B; uint gathers
//      (2 bf16 channels/lane, 2 edges/wave-instruction); f32 accumulation ----
template <bool FINAL>
__global__ void hop_kernel(const unsigned int* __restrict__ ent_src,  // bf16-pair table
                           const float* __restrict__ rel_src,
                           const int* __restrict__ row_start,
                           const int* __restrict__ packed,
                           unsigned int* __restrict__ ent_next,       // FINAL=false (bf16 pairs)
                           const float2* __restrict__ ent0,           // FINAL=true
                           const float2* __restrict__ drug0,          // FINAL=true
                           float2* __restrict__ out_ent,              // FINAL=true
                           float2* __restrict__ out_drug,             // FINAL=true
                           int n_rows, int n_drugs) {
    __shared__ float rel_lds[16 * 64];
    for (int i = threadIdx.x; i < 16 * 64; i += blockDim.x) rel_lds[i] = rel_src[i];
    __syncthreads();

    const int lane = threadIdx.x & 63;
    const int half = lane >> 5;               // 0: edge A, 1: edge B
    const int c = lane & 31;                  // channel pair index (ch 2c, 2c+1)
    const int wave = blockIdx.x * (blockDim.x >> 6) + (threadIdx.x >> 6);
    const int nw = gridDim.x * (blockDim.x >> 6);

    for (int r = wave; r < n_rows; r += nw) {
        const int start = row_start[r];
        const int deg = row_start[r + 1] - start;
        float a00 = 0.f, a01 = 0.f, a10 = 0.f, a11 = 0.f;
        float a20 = 0.f, a21 = 0.f, a30 = 0.f, a31 = 0.f;
        for (int base = 0; base < deg; base += 64) {
            int rem = deg - base;
            if (rem > 64) rem = 64;
            int pk = 0;
            if (lane < rem) pk = packed[start + base + lane];
            const int npairs = (rem + 1) >> 1;
            for (int i = 0; i < npairs; i += 4) {
                // 4 pair-slots -> 8 edges in flight across the two wave halves
                int e0 = 2 * (i + 0) + half;
                int e1 = 2 * (i + 1) + half;
                int e2 = 2 * (i + 2) + half;
                int e3 = 2 * (i + 3) + half;
                int p0 = __shfl(pk, e0 & 63), p1 = __shfl(pk, e1 & 63);
                int p2 = __shfl(pk, e2 & 63), p3 = __shfl(pk, e3 & 63);
                unsigned int u0 = 0, u1 = 0, u2 = 0, u3 = 0;
                if (e0 < rem) u0 = ent_src[(size_t)(p0 & 131071) * 32 + c];
                if (e1 < rem) u1 = ent_src[(size_t)(p1 & 131071) * 32 + c];
                if (e2 < rem) u2 = ent_src[(size_t)(p2 & 131071) * 32 + c];
                if (e3 < rem) u3 = ent_src[(size_t)(p3 & 131071) * 32 + c];
                const float2 r0 = *(const float2*)&rel_lds[((p0 >> 17) & 15) * 64 + 2 * c];
                const float2 r1 = *(const float2*)&rel_lds[((p1 >> 17) & 15) * 64 + 2 * c];
                const float2 r2 = *(const float2*)&rel_lds[((p2 >> 17) & 15) * 64 + 2 * c];
                const float2 r3 = *(const float2*)&rel_lds[((p3 >> 17) & 15) * 64 + 2 * c];
                a00 = fmaf(b2f(u0 & 0xFFFFu), r0.x, a00);
                a01 = fmaf(b2f(u0 >> 16), r0.y, a01);
                a10 = fmaf(b2f(u1 & 0xFFFFu), r1.x, a10);
                a11 = fmaf(b2f(u1 >> 16), r1.y, a11);
                a20 = fmaf(b2f(u2 & 0xFFFFu), r2.x, a20);
                a21 = fmaf(b2f(u2 >> 16), r2.y, a21);
                a30 = fmaf(b2f(u3 & 0xFFFFu), r3.x, a30);
                a31 = fmaf(b2f(u3 >> 16), r3.y, a31);
            }
        }
        float a0 = (a00 + a10) + (a20 + a30);   // channel 2c partial (this half's edges)
        float a1 = (a01 + a11) + (a21 + a31);   // channel 2c+1 partial
        a0 += __shfl_xor(a0, 32);               // combine edge halves
        a1 += __shfl_xor(a1, 32);
        const float denom = (float)(deg > 0 ? deg : 1);
        a0 /= denom;
        a1 /= denom;
        float ss = a0 * a0 + a1 * a1;
#pragma unroll
        for (int off = 16; off > 0; off >>= 1) ss += __shfl_xor(ss, off);
        const float inv = 1.0f / fmaxf(sqrtf(ss), 1e-12f);
        const float e2_0 = a0 * inv, e2_1 = a1 * inv;
        if (!FINAL) {
            if (half == 0)
                ent_next[(size_t)r * 32 + c] = f2b_u32(e2_0) | (f2b_u32(e2_1) << 16);
        } else {
            if (half == 0) {
                const unsigned int e1u = ent_src[(size_t)r * 32 + c];  // ent1 row (bf16 pair)
                const float s0 = b2f(e1u & 0xFFFFu) + e2_0;
                const float s1 = b2f(e1u >> 16) + e2_1;
                const float2 base0 = ent0[(size_t)r * 32 + c];
                float2 o;
                o.x = base0.x + s0;
                o.y = base0.y + s1;
                out_ent[(size_t)r * 32 + c] = o;
                if (r < n_drugs) {
                    const float2 based = drug0[(size_t)r * 32 + c];
                    float2 od;
                    od.x = based.x + s0;
                    od.y = based.y + s1;
                    out_drug[(size_t)r * 32 + c] = od;
                }
            }
        }
    }
}

// rel1 = l2norm(rel0); rel2 = l2norm(rel1) (= rel1); rel_res = rel0 + rel1 + rel2.
__global__ void rel_kernel(const float* __restrict__ rel0, float* __restrict__ rel1_out,
                           float* __restrict__ out_rel, int n_rel) {
    int lane = threadIdx.x & 63;
    int wave = threadIdx.x >> 6;
    if (wave >= n_rel) return;
    float v = rel0[wave * 64 + lane];
    float ss = v * v;
#pragma unroll
    for (int off = 32; off > 0; off >>= 1) ss += __shfl_xor(ss, off);
    float r1 = v / fmaxf(sqrtf(ss), 1e-12f);
    float ss2 = r1 * r1;
#pragma unroll
    for (int off = 32; off > 0; off >>= 1) ss2 += __shfl_xor(ss2, off);
    float r2 = r1 / fmaxf(sqrtf(ss2), 1e-12f);
    rel1_out[wave * 64 + lane] = r1;
    out_rel[wave * 64 + lane] = v + r1 + r2;
}

extern "C" void kernel_launch(void* const* d_in, const int* in_sizes, int n_in,
                              void* d_out, int out_size, void* d_ws, size_t ws_size,
                              hipStream_t stream) {
    const float* drug_emb = (const float*)d_in[0];
    const float* entity_emb = (const float*)d_in[1];
    const float* relation_emb = (const float*)d_in[2];
    const int* edge_index = (const int*)d_in[3];
    const int* edge_type = (const int*)d_in[4];

    const int n_drugs = in_sizes[0] / 64;   // 2000
    const int n_ent = in_sizes[1] / 64;     // 100000
    const int n_rel = in_sizes[2] / 64;     // 16
    const int E = in_sizes[4];              // 1250000

    const int* heads = edge_index;
    const int* tails = edge_index + E;

    const int nchunks = (E + CHUNK - 1) / CHUNK;          // 153
    const int nb = (n_ent + (1 << BSHIFT) - 1) >> BSHIFT; // 391
    const int L = nb * nchunks;                           // ~59,823
    const int nscanG = (L + 1023) / 1024;                 // ~59

    // ws carve-up (int units).
    int* packed = (int*)d_ws;                             // E
    int* unionA = packed + ((E + 1) & ~1);                // max(E, n_ent*32) ints
    int* staging = unionA;                                // E ints (dies at finalize)
    unsigned int* ent_bf16 = (unsigned int*)unionA;       // n_ent*32 uints (born after)
    size_t unionA_ints = (size_t)n_ent * 32;              // 3.2M >= E
    if (unionA_ints < (size_t)E) unionA_ints = (size_t)E;
    unsigned int* ent1 = (unsigned int*)(unionA + unionA_ints);  // n_ent*32 uints
    int* G = unionA + unionA_ints + (size_t)n_ent * 32;   // L
    int* Gscan = G + L;                                   // L
    int* blocksum = Gscan + L;                            // 128
    int* blockoff = blocksum + 128;                       // 128
    int* row_start = blockoff + 128;                      // n_ent+1
    float* rel1 = (float*)(row_start + n_ent + 1);        // n_rel*64

    float* out_ent = (float*)d_out;
    float* out_drug = out_ent + (size_t)n_ent * 64;
    float* out_rel = out_drug + (size_t)n_drugs * 64;

    local_hist_kernel<<<nchunks, ABLOCK, 0, stream>>>(heads, G, E, nchunks, nb);
    scan_block<<<nscanG, 1024, 0, stream>>>(G, Gscan, blocksum, L);
    scan_block<<<1, 1024, 0, stream>>>(blocksum, blockoff, nullptr, nscanG);
    place_stage_kernel<<<nchunks, ABLOCK, 0, stream>>>(heads, tails, edge_type, Gscan,
                                                       blockoff, staging, E, nchunks, nb);
    finalize_kernel<<<nb, 512, 0, stream>>>(staging, Gscan, blockoff, packed, row_start,
                                            E, nchunks, nb, n_ent);
    // staging is dead now; convert entity table into its space (stream-ordered).
    cvt_bf16_kernel<<<2048, 256, 0, stream>>>((const uint4*)entity_emb,
                                              (uint2*)ent_bf16, n_ent * 16);
    hop_kernel<false><<<2048, 256, 0, stream>>>(ent_bf16, relation_emb, row_start, packed,
                                                ent1, nullptr, nullptr, nullptr, nullptr,
                                                n_ent, 0);
    rel_kernel<<<1, 1024, 0, stream>>>(relation_emb, rel1, out_rel, n_rel);
    hop_kernel<true><<<2048, 256, 0, stream>>>(ent1, rel1, row_start, packed,
                                               nullptr, (const float2*)entity_emb,
                                               (const float2*)drug_emb,
                                               (float2*)out_ent, (float2*)out_drug,
                                               n_ent, n_drugs);
}